// Round 3
// baseline (98.241 us; speedup 1.0000x reference)
//
#include <hip/hip_runtime.h>

// NeighborGatherLayer3D: out[b,l,k,t,c] = (idx[l,k] >= 0) ? in[b, idx[l,k], t, c] : 0
// B=32, L=1855, K=7, T=32, C=8  -> per-(b,l,k) chunk = T*C = 256 floats = 64 float4
constexpr int B = 32;
constexpr int L = 1855;
constexpr int K = 7;
constexpr int TC4 = 64;                 // float4 per chunk (T*C/4)
constexpr long long TOTAL4 = (long long)B * L * K * TC4;  // 26,593,280
constexpr int ILP = 4;                  // elements per thread
constexpr int BLK = 256;
constexpr int PER_BLOCK = BLK * ILP;    // 1024 float4 per block; TOTAL4 % 1024 == 0

typedef float f32x4 __attribute__((ext_vector_type(4)));

__global__ __launch_bounds__(BLK) void neighbor_gather_kernel(
    const f32x4* __restrict__ src4,      // inputs as float4: (B*L) x 64
    const int* __restrict__ nbr,         // (L, K)
    f32x4* __restrict__ out4)            // (B*L*K) x 64
{
    const int base = blockIdx.x * PER_BLOCK + threadIdx.x;

    int e[ILP], ni[ILP];
    // Phase 1: issue all index loads (independent, mostly L2-hit broadcast)
#pragma unroll
    for (int j = 0; j < ILP; ++j) {
        e[j] = base + j * BLK;
        const int chunk = e[j] >> 6;     // (b*L + l)*K + k
        const int k  = chunk % K;        // magic-mul
        const int bl = chunk / K;
        const int l  = bl % L;           // magic-mul
        ni[j] = nbr[l * K + k];          // wave-uniform within each 64-lane group
    }
    // Phase 2: issue all data loads (independent -> 4 outstanding HBM/L3 reads)
    f32x4 v[ILP];
#pragma unroll
    for (int j = 0; j < ILP; ++j) {
        v[j] = (f32x4){0.f, 0.f, 0.f, 0.f};
        if (ni[j] >= 0) {
            const int bl = (e[j] >> 6) / K;
            const int b  = bl / L;
            v[j] = src4[(size_t)(b * L + ni[j]) * TC4 + (e[j] & 63)];
        }
    }
    // Phase 3: nontemporal streaming stores (write-once 425 MB; keep caches for input)
#pragma unroll
    for (int j = 0; j < ILP; ++j) {
        __builtin_nontemporal_store(v[j], &out4[e[j]]);
    }
}

extern "C" void kernel_launch(void* const* d_in, const int* in_sizes, int n_in,
                              void* d_out, int out_size, void* d_ws, size_t ws_size,
                              hipStream_t stream) {
    const f32x4* src4 = (const f32x4*)d_in[0];     // inputs (B,L,T,C) float32
    const int*   nbr  = (const int*)d_in[1];       // neighbor_indices (L,K) int32
    f32x4*       out4 = (f32x4*)d_out;

    const int nblocks = (int)(TOTAL4 / PER_BLOCK); // 25,970 exactly
    neighbor_gather_kernel<<<nblocks, BLK, 0, stream>>>(src4, nbr, out4);
}

// Round 4
// 69.327 us; speedup vs baseline: 1.4171x; 1.4171x over previous
//
#include <hip/hip_runtime.h>

// NeighborGatherLayer3D: out[b,l,k,t,c] = (idx[l,k] >= 0) ? in[b, idx[l,k], t, c] : 0
// B=32, L=1855, K=7, T=32, C=8  -> per-(b,l,k) chunk = T*C = 256 floats = 64 float4
constexpr int B = 32;
constexpr int L = 1855;
constexpr int K = 7;
constexpr int TC4 = 64;                 // float4 per chunk (T*C/4)
constexpr long long TOTAL4 = (long long)B * L * K * TC4;  // 26,593,280
constexpr int BLK = 256;
constexpr int NBLK = (int)(TOTAL4 / BLK);  // 103,880 (divisible by 8)
constexpr int NXCD = 8;
constexpr int CPX = NBLK / NXCD;        // 12,985 blocks per XCD = exactly 4 b-slices

typedef float f32x4 __attribute__((ext_vector_type(4)));

__global__ __launch_bounds__(BLK) void neighbor_gather_kernel(
    const f32x4* __restrict__ src4,      // inputs as float4: (B*L) x 64
    const int* __restrict__ nbr,         // (L, K)
    f32x4* __restrict__ out4)            // (B*L*K) x 64
{
    // XCD-aware swizzle: dispatch is round-robin over 8 XCDs, so blocks with
    // bid%8==x run on XCD x. Give XCD x the contiguous logical range
    // [x*CPX, (x+1)*CPX) == batches b in [4x, 4x+4) -> per-XCD random-read
    // working set is one 1.9 MB b-slice, resident in its 4 MB L2.
    const int bid = blockIdx.x;
    const int logical = (bid & 7) * CPX + (bid >> 3);

    const int e = logical * BLK + threadIdx.x;      // float4 element index
    const int chunk = e >> 6;            // (b*L + l)*K + k
    const int w = e & 63;                // float4 offset within chunk

    const int k  = chunk % K;            // magic-mul
    const int bl = chunk / K;            // b*L + l
    const int l  = bl % L;               // magic-mul

    // Wave-uniform load (all 64 lanes of a wave share one chunk)
    const int ni = nbr[l * K + k];

    f32x4 v = {0.f, 0.f, 0.f, 0.f};
    if (ni >= 0) {
        const int b = bl / L;
        v = src4[(size_t)(b * L + ni) * TC4 + w];
    }
    // Output is 425 MB write-once: nontemporal streaming store
    __builtin_nontemporal_store(v, &out4[e]);
}

extern "C" void kernel_launch(void* const* d_in, const int* in_sizes, int n_in,
                              void* d_out, int out_size, void* d_ws, size_t ws_size,
                              hipStream_t stream) {
    const f32x4* src4 = (const f32x4*)d_in[0];     // inputs (B,L,T,C) float32
    const int*   nbr  = (const int*)d_in[1];       // neighbor_indices (L,K) int32
    f32x4*       out4 = (f32x4*)d_out;

    neighbor_gather_kernel<<<NBLK, BLK, 0, stream>>>(src4, nbr, out4);
}